// Round 5
// baseline (152.947 us; speedup 1.0000x reference)
//
#include <hip/hip_runtime.h>

#define BB 8
#define SS 2048
#define DD 128
#define ROWS 32            // q rows per block (2 row-groups of 16)
#define NW 8               // waves per block (512 threads)
#define CTW 16             // col-tiles (of 16) per wave -> 256 cols/wave
#define CAP 48             // candidate cap per row

typedef short bf16x8 __attribute__((ext_vector_type(8)));
typedef float f32x4 __attribute__((ext_vector_type(4)));

template <int I> struct IC { static constexpr int value = I; };
template <int I, int N, typename F>
__device__ __forceinline__ void sfor(F&& f) {
  if constexpr (I < N) { f(IC<I>{}); sfor<I + 1, N>((F&&)f); }
}

__device__ __forceinline__ short f2bf(float x) {
  return __builtin_bit_cast(short, (__bf16)x);
}
__device__ __forceinline__ unsigned pk2(float a, float b) {
  return (unsigned)(unsigned short)f2bf(a) |
         ((unsigned)(unsigned short)f2bf(b) << 16);
}

template <int N> __device__ __forceinline__ void wait_vm() {
  if constexpr (N >= 6)      asm volatile("s_waitcnt vmcnt(6)" ::: "memory");
  else if constexpr (N == 5) asm volatile("s_waitcnt vmcnt(5)" ::: "memory");
  else if constexpr (N == 4) asm volatile("s_waitcnt vmcnt(4)" ::: "memory");
  else if constexpr (N == 3) asm volatile("s_waitcnt vmcnt(3)" ::: "memory");
  else if constexpr (N == 2) asm volatile("s_waitcnt vmcnt(2)" ::: "memory");
  else if constexpr (N == 1) asm volatile("s_waitcnt vmcnt(1)" ::: "memory");
  else                       asm volatile("s_waitcnt vmcnt(0)" ::: "memory");
}

// async DMA one 1KB quarter-tile: 64 lanes x 16B, LDS dest = uniform base + lane*16
__device__ __forceinline__ void stage1(const short* g, short* l) {
  __builtin_amdgcn_global_load_lds(
      (const __attribute__((address_space(1))) void*)g,
      (__attribute__((address_space(3))) void*)l, 16, 0, 0);
}

// ---- prep: Khi = bf16(K) in MFMA B-fragment order ----
// Frag (b,ct,s,lane): lane(quad,m16) holds K[b][ct*16+m16][s*32+quad*8 .. +8]
__global__ __launch_bounds__(256)
void ksplit(const float* __restrict__ K, short* __restrict__ Khi) {
  const int lin  = blockIdx.x * 256 + threadIdx.x;   // 262144 frags
  const int b    = lin >> 15;
  const int rem  = lin & 32767;
  const int ct   = rem >> 8;
  const int s    = (rem >> 6) & 3;
  const int lane = rem & 63;
  const int quad = lane >> 4, m16 = lane & 15;
  const size_t elem = (size_t)(b * SS + ct * 16 + m16) * DD + s * 32 + quad * 8;
  const float4 v0 = *(const float4*)(K + elem);
  const float4 v1 = *(const float4*)(K + elem + 4);
  const float f[8] = {v0.x, v0.y, v0.z, v0.w, v1.x, v1.y, v1.z, v1.w};
  bf16x8 h;
#pragma unroll
  for (int e = 0; e < 8; ++e) h[e] = f2bf(f[e]);
  *(bf16x8*)(Khi + (size_t)lin * 8) = h;      // fragment order
}

// ---- fused entmax attention, 32 rows/block ----
// Each wave: 2 Q row-groups x 256 cols against the same streamed Khi tiles
// (halves K traffic, grid 512 = fully co-resident at 2 blocks/CU).
__global__ __launch_bounds__(512) __attribute__((amdgpu_waves_per_eu(4)))
void attn(const float* __restrict__ Q, const short* __restrict__ Khi,
          const float* __restrict__ K, const float* __restrict__ V,
          float* __restrict__ Out) {
  __shared__ short kring[NW][8][512];          // per-wave 8-slot 1KB ring (64 KiB)
  __shared__ __align__(16) char ubuf[12288];   // Qs (phase 0) | rbuf+scol (after)
  unsigned short (*Qs)[136] = (unsigned short (*)[136])ubuf;        // [32][136]
  float (*rbuf)[CAP] = (float (*)[CAP])ubuf;                        // [32][48]
  int   (*scol)[CAP] = (int (*)[CAP])(ubuf + ROWS * CAP * 4);       // [32][48]
  __shared__ float exM[NW][ROWS];
  __shared__ int   rcnt[ROWS];
  __shared__ int   rovf[ROWS];                 // per-row overflow flag
  __shared__ float tauB[ROWS], ZB[ROWS];

  const int tid  = threadIdx.x;
  const int lane = tid & 63;
  const int wid  = __builtin_amdgcn_readfirstlane(tid >> 6);  // 0..7
  const int quad = lane >> 4, m16 = lane & 15;
  const int b    = blockIdx.x & 7;             // batch -> XCD pinning
  const int qt   = blockIdx.x >> 3;            // 0..63

  const float* Qb = Q + (size_t)(b * SS + qt * ROWS) * DD;
  const float* Kb = K + (size_t)b * SS * DD;
  const float* Vb = V + (size_t)b * SS * DD;
  float*       Ob = Out + (size_t)(b * SS + qt * ROWS) * DD;
  const short* KHb = Khi + (size_t)b * SS * DD;

  if (tid < ROWS) { rcnt[tid] = 0; rovf[tid] = 0; }

  // ---- stage Q once: bf16(0.5*q), A-operand layout; 8 floats/thread ----
  {
    const int row = tid >> 4, d = (tid & 15) * 8;
    const float4 v0 = *(const float4*)&Qb[row * DD + d];
    const float4 v1 = *(const float4*)&Qb[row * DD + d + 4];
    ushort4 h0, h1;
    h0.x = (unsigned short)f2bf(0.5f * v0.x);
    h0.y = (unsigned short)f2bf(0.5f * v0.y);
    h0.z = (unsigned short)f2bf(0.5f * v0.z);
    h0.w = (unsigned short)f2bf(0.5f * v0.w);
    h1.x = (unsigned short)f2bf(0.5f * v1.x);
    h1.y = (unsigned short)f2bf(0.5f * v1.y);
    h1.z = (unsigned short)f2bf(0.5f * v1.z);
    h1.w = (unsigned short)f2bf(0.5f * v1.w);
    *(ushort4*)&Qs[row][d]     = h0;
    *(ushort4*)&Qs[row][d + 4] = h1;
  }
  __syncthreads();

  // ---- phase 1 setup: prefetch ring, load both A-fragments ----
  short* ring = &kring[wid][0][0];
  const short* gw = KHb + ((size_t)(wid * CTW) << 11) + lane * 8;  // +q*512 shorts

  sfor<0, 6>([&](auto pc) {                   // quarters 0..5 in flight
    constexpr int p = pc.value;
    stage1(gw + p * 512, ring + p * 512);
  });

  bf16x8 qh[2][4];
#pragma unroll
  for (int g = 0; g < 2; ++g)
#pragma unroll
    for (int s = 0; s < 4; ++s)
      qh[g][s] = *(const bf16x8*)&Qs[g * 16 + m16][s * 32 + quad * 8];

  // ---- phase 1: z_a = bf16(0.5Q) * Khi^T, 64 quarters, 2 per iter ----
  // iter i: quarters 2i,2i+1. vmcnt(4) => they landed (issued 3 iters back).
  // lgkm(0) => slots to overwrite had reads retired. 2 ds_read + 4 MFMA.
  unsigned zpk[2][CTW][2];                     // packed bf16 z_a, 64 VGPRs
  float mx[2][4] = {{-1e38f, -1e38f, -1e38f, -1e38f},
                    {-1e38f, -1e38f, -1e38f, -1e38f}};
  f32x4 accA = {0.f, 0.f, 0.f, 0.f}, accB = {0.f, 0.f, 0.f, 0.f};

  sfor<0, 32>([&](auto ii) {
    constexpr int i = ii.value;
    constexpr int left = 62 - 2 * i;
    wait_vm<(left < 0 ? 0 : (left > 4 ? 4 : left))>();
    asm volatile("s_waitcnt lgkmcnt(0)" ::: "memory");
    if constexpr (2 * i + 7 < 64) {
      stage1(gw + (2 * i + 6) * 512, ring + ((2 * i + 6) & 7) * 512);
      stage1(gw + (2 * i + 7) * 512, ring + ((2 * i + 7) & 7) * 512);
    }
    const bf16x8 b0 = *(const bf16x8*)(ring + (((2 * i)     & 7) << 9) + lane * 8);
    const bf16x8 b1 = *(const bf16x8*)(ring + (((2 * i + 1) & 7) << 9) + lane * 8);
    constexpr int s0 = (2 * i) & 3;
    constexpr int s1 = s0 + 1;
    if constexpr (s0 == 0) {
      accA = f32x4{0.f, 0.f, 0.f, 0.f};
      accB = f32x4{0.f, 0.f, 0.f, 0.f};
    }
    accA = __builtin_amdgcn_mfma_f32_16x16x32_bf16(qh[0][s0], b0, accA, 0, 0, 0);
    accB = __builtin_amdgcn_mfma_f32_16x16x32_bf16(qh[1][s0], b0, accB, 0, 0, 0);
    accA = __builtin_amdgcn_mfma_f32_16x16x32_bf16(qh[0][s1], b1, accA, 0, 0, 0);
    accB = __builtin_amdgcn_mfma_f32_16x16x32_bf16(qh[1][s1], b1, accB, 0, 0, 0);
    if constexpr (s1 == 3) {
      constexpr int ct = i >> 1;
#pragma unroll
      for (int j = 0; j < 4; ++j) {
        mx[0][j] = fmaxf(mx[0][j], accA[j]);
        mx[1][j] = fmaxf(mx[1][j], accB[j]);
      }
      zpk[0][ct][0] = pk2(accA[0], accA[1]);
      zpk[0][ct][1] = pk2(accA[2], accA[3]);
      zpk[1][ct][0] = pk2(accB[0], accB[1]);
      zpk[1][ct][1] = pk2(accB[2], accB[3]);
    }
  });
  // lane holds packed z_a[row=g*16+4*quad+j][col = wid*256 + ct*16 + m16]

  // ---- cross-wave row max ----
#pragma unroll
  for (int g = 0; g < 2; ++g)
#pragma unroll
    for (int j = 0; j < 4; ++j)
#pragma unroll
      for (int s = 1; s <= 8; s <<= 1)
        mx[g][j] = fmaxf(mx[g][j], __shfl_xor(mx[g][j], s));
  if (m16 == 0) {
#pragma unroll
    for (int g = 0; g < 2; ++g)
#pragma unroll
      for (int j = 0; j < 4; ++j) exM[wid][g * 16 + 4 * quad + j] = mx[g][j];
  }
  __syncthreads();
  float M4[2][4];
#pragma unroll
  for (int g = 0; g < 2; ++g)
#pragma unroll
    for (int j = 0; j < 4; ++j) {
      float m = -1e38f;
#pragma unroll
      for (int w = 0; w < NW; ++w) m = fmaxf(m, exM[w][g * 16 + 4 * quad + j]);
      M4[g][j] = m;
    }

  // ---- compact candidates: z_pk > M - 1.35 (1 + screen err + pack rounding) ----
  // (rbuf/scol alias Qs; all Qs reads completed before the exM barrier)
  sfor<0, CTW>([&](auto cc) {
    constexpr int ct = cc.value;
    const int col = wid * 256 + ct * 16 + m16;
#pragma unroll
    for (int g = 0; g < 2; ++g) {
      float v[4];
      v[0] = __uint_as_float(zpk[g][ct][0] << 16);
      v[1] = __uint_as_float(zpk[g][ct][0] & 0xffff0000u);
      v[2] = __uint_as_float(zpk[g][ct][1] << 16);
      v[3] = __uint_as_float(zpk[g][ct][1] & 0xffff0000u);
#pragma unroll
      for (int j = 0; j < 4; ++j) {
        const int row = g * 16 + 4 * quad + j;
        if (v[j] > M4[g][j] - 1.35f) {
          const int pos = atomicAdd(&rcnt[row], 1);
          if (pos < CAP) { scol[row][pos] = col; rbuf[row][pos] = v[j]; }
          else rovf[row] = 1;
        }
      }
    }
  });
  __syncthreads();   // candidate tables complete

  // ======== wave-local tail: wave wid owns rows 4*wid .. 4*wid+3 ========
  const int rr32 = lane >> 5;
  const int l32  = lane & 31;

#pragma unroll
  for (int p = 0; p < 2; ++p) {
    const int row = 4 * wid + 2 * p + rr32;
    const int nA = rcnt[4 * wid + 2 * p]     < CAP ? rcnt[4 * wid + 2 * p]     : CAP;
    const int nB = rcnt[4 * wid + 2 * p + 1] < CAP ? rcnt[4 * wid + 2 * p + 1] : CAP;
    const int nr  = rr32 ? nB : nA;
    const int nmx = nA > nB ? nA : nB;

    // ---- refine EXACTLY (2 rows in parallel, 32 lanes each): z = 0.5*dot ----
    {
      const float4 q4 = *(const float4*)&Qb[row * DD + l32 * 4];
      for (int i = 0; i < nmx; ++i) {
        const bool act = i < nr;
        const int c = act ? scol[row][i] : scol[row][0];
        const float4 k4 = *(const float4*)&Kb[(size_t)c * DD + l32 * 4];
        float t = q4.x * k4.x + q4.y * k4.y + q4.z * k4.z + q4.w * k4.w;
#pragma unroll
        for (int s = 1; s <= 16; s <<= 1) t += __shfl_xor(t, s);
        if (act && l32 == 0) rbuf[row][i] = 0.5f * t;
      }
    }
    // rbuf written+read by this same wave only -> no barrier

    // ---- bisection: 32 lanes per row, candidates in 2 registers ----
    {
      const float a0 = (l32 < nr)      ? rbuf[row][l32]      : -1e38f;
      const float a1 = (l32 + 32 < nr) ? rbuf[row][l32 + 32] : -1e38f;
      float Mr = fmaxf(a0, a1);
#pragma unroll
      for (int s = 1; s <= 16; s <<= 1) Mr = fmaxf(Mr, __shfl_xor(Mr, s));
      float tmn = Mr - 1.0f, tmx = Mr - 0.022097086912079608f;  // S^(1-alpha)
      float tau = 0.5f * (tmn + tmx), Zr = 0.f;
      for (int it = 0; it < 100; ++it) {
        tau = 0.5f * (tmn + tmx);
        const float t0 = fmaxf(a0 - tau, 0.f);
        const float t1 = fmaxf(a1 - tau, 0.f);
        float zp = fmaf(t0, t0, t1 * t1);
#pragma unroll
        for (int s = 1; s <= 16; s <<= 1) zp += __shfl_xor(zp, s);
        Zr = zp;
        const float nmn = (zp >= 1.f) ? tau : tmn;
        const float nmx2 = (zp >= 1.f) ? tmx : tau;
        const bool ch = (nmn != tmn) || (nmx2 != tmx);
        tmn = nmn; tmx = nmx2;
        if (!__any(ch)) break;   // fixed point: faithful to 100 iters
      }
      if (l32 == 0) { tauB[row] = tau; ZB[row] = Zr; }
    }

    // ---- output (2 rows in parallel): O = sum p_i * V[col_i] ----
    if (!rovf[row]) {
      const float tau = tauB[row];
      const float iz  = 1.0f / ZB[row];
      float4 o = {0.f, 0.f, 0.f, 0.f};
      for (int i = 0; i < nr; ++i) {
        const float rv = rbuf[row][i];         // same addr per half -> broadcast
        const float tt = fmaxf(rv - tau, 0.f);
        const float pi = tt * tt * iz;
        const int   c  = scol[row][i];
        const float4 v4 = *(const float4*)&Vb[(size_t)c * DD + l32 * 4];
        o.x = fmaf(pi, v4.x, o.x);
        o.y = fmaf(pi, v4.y, o.y);
        o.z = fmaf(pi, v4.z, o.z);
        o.w = fmaf(pi, v4.w, o.w);
      }
      *(float4*)&Ob[row * DD + l32 * 4] = o;
    }
  }

  // ---- exact wave-local dense fallback (candidate overflow; ~unreachable) ----
#pragma unroll
  for (int rr = 0; rr < 4; ++rr) {
    const int frow = 4 * wid + rr;
    if (!rovf[frow]) continue;
    float* zr = (float*)&kring[wid][0][0];     // 8 KB = 2048 f32, wave-private
    for (int c0 = 0; c0 < 32; ++c0) {
      const int c = c0 * 64 + lane;
      const float* kp = &Kb[(size_t)c * DD];
      float t = 0.f;
      for (int d = 0; d < DD; d += 4) {
        const float4 qv = *(const float4*)&Qb[frow * DD + d];
        const float4 kv = *(const float4*)&kp[d];
        t = fmaf(qv.x, kv.x, t); t = fmaf(qv.y, kv.y, t);
        t = fmaf(qv.z, kv.z, t); t = fmaf(qv.w, kv.w, t);
      }
      zr[c] = 0.5f * t;
    }
    float Mr = -1e38f;
    for (int c0 = 0; c0 < 32; ++c0) Mr = fmaxf(Mr, zr[c0 * 64 + lane]);
#pragma unroll
    for (int s = 1; s <= 32; s <<= 1) Mr = fmaxf(Mr, __shfl_xor(Mr, s));
    float tmn = Mr - 1.0f, tmx = Mr - 0.022097086912079608f;
    float tau = 0.5f * (tmn + tmx), Zr = 0.f;
    for (int it = 0; it < 100; ++it) {
      tau = 0.5f * (tmn + tmx);
      float zp = 0.f;
      for (int c0 = 0; c0 < 32; ++c0) {
        const float tt = fmaxf(zr[c0 * 64 + lane] - tau, 0.f);
        zp = fmaf(tt, tt, zp);
      }
#pragma unroll
      for (int s = 1; s <= 32; s <<= 1) zp += __shfl_xor(zp, s);
      Zr = zp;
      const float nmn = (zp >= 1.f) ? tau : tmn;
      const float nmx2 = (zp >= 1.f) ? tmx : tau;
      const bool ch = (nmn != tmn) || (nmx2 != tmx);
      tmn = nmn; tmx = nmx2;
      if (!__any(ch)) break;
    }
    const float iz = 1.0f / Zr;
    float2 o = {0.f, 0.f};
    for (int c = 0; c < SS; ++c) {
      const float tt = fmaxf(zr[c] - tau, 0.f);   // broadcast -> uniform branch
      if (tt > 0.f) {
        const float pi = tt * tt * iz;
        const float2 v2 = *(const float2*)&Vb[(size_t)c * DD + lane * 2];
        o.x = fmaf(pi, v2.x, o.x);
        o.y = fmaf(pi, v2.y, o.y);
      }
    }
    *(float2*)&Ob[frow * DD + lane * 2] = o;
  }
}

extern "C" void kernel_launch(void* const* d_in, const int* in_sizes, int n_in,
                              void* d_out, int out_size, void* d_ws, size_t ws_size,
                              hipStream_t stream) {
  const float* Q = (const float*)d_in[0];
  const float* K = (const float*)d_in[1];
  const float* V = (const float*)d_in[2];
  float* out = (float*)d_out;
  short* Khi = (short*)d_ws;                      // 4 MiB, fragment order

  hipLaunchKernelGGL(ksplit, dim3(BB * SS * DD / (256 * 8)), dim3(256), 0, stream,
                     K, Khi);
  hipLaunchKernelGGL(attn, dim3(BB * (SS / ROWS)), dim3(512), 0, stream,
                     Q, Khi, K, V, out);
}

// Round 6
// 141.027 us; speedup vs baseline: 1.0845x; 1.0845x over previous
//
#include <hip/hip_runtime.h>

#define BB 8
#define SS 2048
#define DD 128
#define ROWS 16            // q rows per screen block
#define NW 8               // waves per screen block (512 threads)
#define CTW 16             // col-tiles (of 16) per wave -> 256 cols/wave
#define CAP 24             // candidate cap per row (global table)

typedef short bf16x8 __attribute__((ext_vector_type(8)));
typedef float f32x4 __attribute__((ext_vector_type(4)));

template <int I> struct IC { static constexpr int value = I; };
template <int I, int N, typename F>
__device__ __forceinline__ void sfor(F&& f) {
  if constexpr (I < N) { f(IC<I>{}); sfor<I + 1, N>((F&&)f); }
}

__device__ __forceinline__ short f2bf(float x) {
  return __builtin_bit_cast(short, (__bf16)x);
}
__device__ __forceinline__ unsigned pk2(float a, float b) {
  return (unsigned)(unsigned short)f2bf(a) |
         ((unsigned)(unsigned short)f2bf(b) << 16);
}

template <int N> __device__ __forceinline__ void wait_vm() {
  if constexpr (N >= 6)      asm volatile("s_waitcnt vmcnt(6)" ::: "memory");
  else if constexpr (N == 5) asm volatile("s_waitcnt vmcnt(5)" ::: "memory");
  else if constexpr (N == 4) asm volatile("s_waitcnt vmcnt(4)" ::: "memory");
  else if constexpr (N == 3) asm volatile("s_waitcnt vmcnt(3)" ::: "memory");
  else if constexpr (N == 2) asm volatile("s_waitcnt vmcnt(2)" ::: "memory");
  else if constexpr (N == 1) asm volatile("s_waitcnt vmcnt(1)" ::: "memory");
  else                       asm volatile("s_waitcnt vmcnt(0)" ::: "memory");
}

// async DMA one 1KB quarter-tile: 64 lanes x 16B, LDS dest = uniform base + lane*16
__device__ __forceinline__ void stage1(const short* g, short* l) {
  __builtin_amdgcn_global_load_lds(
      (const __attribute__((address_space(1))) void*)g,
      (__attribute__((address_space(3))) void*)l, 16, 0, 0);
}

// ---- prep: Khi = bf16(K) in MFMA B-fragment order; also zero cnt ----
// Frag (b,ct,s,lane): lane(quad,m16) holds K[b][ct*16+m16][s*32+quad*8 .. +8]
__global__ __launch_bounds__(256)
void ksplit(const float* __restrict__ K, short* __restrict__ Khi,
            int* __restrict__ cnt) {
  const int lin  = blockIdx.x * 256 + threadIdx.x;   // 262144 frags
  if (lin < BB * SS) cnt[lin] = 0;                   // re-zero each launch
  const int b    = lin >> 15;
  const int rem  = lin & 32767;
  const int ct   = rem >> 8;
  const int s    = (rem >> 6) & 3;
  const int lane = rem & 63;
  const int quad = lane >> 4, m16 = lane & 15;
  const size_t elem = (size_t)(b * SS + ct * 16 + m16) * DD + s * 32 + quad * 8;
  const float4 v0 = *(const float4*)(K + elem);
  const float4 v1 = *(const float4*)(K + elem + 4);
  const float f[8] = {v0.x, v0.y, v0.z, v0.w, v1.x, v1.y, v1.z, v1.w};
  bf16x8 h;
#pragma unroll
  for (int e = 0; e < 8; ++e) h[e] = f2bf(f[e]);
  *(bf16x8*)(Khi + (size_t)lin * 8) = h;      // fragment order
}

// ---- screen: z_a = bf16(0.5Q)*Khi^T via deep async LDS ring; candidates -> global ----
__global__ __launch_bounds__(512) __attribute__((amdgpu_waves_per_eu(4)))
void screen(const float* __restrict__ Q, const short* __restrict__ Khi,
            int* __restrict__ candC, int* __restrict__ cnt) {
  __shared__ short kring[NW][8][512];          // per-wave 8-slot 1KB ring (64 KiB)
  __shared__ unsigned short Qs[ROWS][136];     // bf16(0.5*Q), A-operand layout
  __shared__ float exM[NW][ROWS];

  const int tid  = threadIdx.x;
  const int lane = tid & 63;
  const int wid  = __builtin_amdgcn_readfirstlane(tid >> 6);  // 0..7
  const int quad = lane >> 4, m16 = lane & 15;
  const int b    = blockIdx.x & 7;             // batch -> XCD pinning
  const int qt   = blockIdx.x >> 3;            // 0..127
  const int rowBase = b * SS + qt * ROWS;      // global row of this block's row 0

  const float* Qb = Q + (size_t)rowBase * DD;
  const short* KHb = Khi + (size_t)b * SS * DD;

  // ---- stage Q once: bf16(0.5*q), A-operand layout ----
  {
    const int row = tid >> 5, d = (tid & 31) * 4;
    const float4 v = *(const float4*)&Qb[row * DD + d];
    ushort4 h;
    h.x = (unsigned short)f2bf(0.5f * v.x);
    h.y = (unsigned short)f2bf(0.5f * v.y);
    h.z = (unsigned short)f2bf(0.5f * v.z);
    h.w = (unsigned short)f2bf(0.5f * v.w);
    *(ushort4*)&Qs[row][d] = h;
  }
  __syncthreads();   // also drains vmcnt -> ring counting below starts clean

  bf16x8 qh[4];
#pragma unroll
  for (int s = 0; s < 4; ++s)
    qh[s] = *(const bf16x8*)&Qs[m16][s * 32 + quad * 8];

  // ---- phase 1: 64 quarter-tiles (1KB each), 8-slot ring, 7-ahead ----
  short* ring = &kring[wid][0][0];
  const short* gw = KHb + ((size_t)(wid * CTW) << 11) + lane * 8;  // +q*512 shorts

  sfor<0, 7>([&](auto pc) {
    constexpr int p = pc.value;
    stage1(gw + p * 512, ring + p * 512);
  });

  unsigned zpk[CTW][2];                        // packed bf16 z_a, 32 VGPRs
  float mx[4] = {-1e38f, -1e38f, -1e38f, -1e38f};
  f32x4 acc = {0.f, 0.f, 0.f, 0.f};

  sfor<0, 64>([&](auto qc) {
    constexpr int q = qc.value;
    wait_vm<(63 - q < 6 ? 63 - q : 6)>();
    asm volatile("s_waitcnt lgkmcnt(0)" ::: "memory");
    if constexpr (q + 7 < 64)
      stage1(gw + (q + 7) * 512, ring + ((q + 7) & 7) * 512);
    const bf16x8 bh = *(const bf16x8*)(ring + ((q & 7) << 9) + lane * 8);
    constexpr int s = q & 3;
    if constexpr (s == 0) acc = f32x4{0.f, 0.f, 0.f, 0.f};
    acc = __builtin_amdgcn_mfma_f32_16x16x32_bf16(qh[s], bh, acc, 0, 0, 0);
    if constexpr (s == 3) {
      constexpr int ct = q >> 2;
#pragma unroll
      for (int j = 0; j < 4; ++j) mx[j] = fmaxf(mx[j], acc[j]);
      zpk[ct][0] = pk2(acc[0], acc[1]);
      zpk[ct][1] = pk2(acc[2], acc[3]);
    }
  });
  // lane holds packed z_a[row=4*quad+j][col = wid*256 + ct*16 + m16]

  // ---- cross-wave row max ----
#pragma unroll
  for (int j = 0; j < 4; ++j)
#pragma unroll
    for (int s = 1; s <= 8; s <<= 1) mx[j] = fmaxf(mx[j], __shfl_xor(mx[j], s));
  if (m16 == 0) {
#pragma unroll
    for (int j = 0; j < 4; ++j) exM[wid][4 * quad + j] = mx[j];
  }
  __syncthreads();
  float M4[4];
#pragma unroll
  for (int j = 0; j < 4; ++j) {
    float m = -1e38f;
#pragma unroll
    for (int w = 0; w < NW; ++w) m = fmaxf(m, exM[w][4 * quad + j]);
    M4[j] = m;
  }

  // ---- compact candidates to GLOBAL: z_pk > M - 1.35 (1 + screen + pack err) ----
  sfor<0, CTW>([&](auto cc) {
    constexpr int ct = cc.value;
    const int col = wid * 256 + ct * 16 + m16;
    float v[4];
    v[0] = __uint_as_float(zpk[ct][0] << 16);
    v[1] = __uint_as_float(zpk[ct][0] & 0xffff0000u);
    v[2] = __uint_as_float(zpk[ct][1] << 16);
    v[3] = __uint_as_float(zpk[ct][1] & 0xffff0000u);
#pragma unroll
    for (int j = 0; j < 4; ++j) {
      if (v[j] > M4[j] - 1.35f) {
        const int rowg = rowBase + 4 * quad + j;
        const int pos = atomicAdd(&cnt[rowg], 1);
        if (pos < CAP) candC[rowg * CAP + pos] = col;
        // pos >= CAP leaves cnt > CAP -> tail takes exact dense fallback
      }
    }
  });
}

// ---- tail: exact refine + bisection + PV. 4 waves, each wave-half owns a row ----
__global__ __launch_bounds__(256)
void tail(const float* __restrict__ Q, const float* __restrict__ K,
          const float* __restrict__ V, const int* __restrict__ candC,
          const int* __restrict__ cnt, float* __restrict__ Out) {
  __shared__ float zv[4][2][CAP];              // refined candidate values
  __shared__ float zscr[SS];                   // dense fallback scratch (8 KB)
  __shared__ int   ovfs[8];
  __shared__ float ftau, fZ;

  const int tid  = threadIdx.x;
  const int w    = tid >> 6;                   // wave 0..3
  const int lane = tid & 63;
  const int rr32 = lane >> 5, l32 = lane & 31;
  const int rowgA = blockIdx.x * 8 + w * 2;    // this wave's first row
  const int rowg  = rowgA + rr32;              // this half's row
  const int b     = rowg >> 11;

  if (tid < 8) ovfs[tid] = 0;
  __syncthreads();

  const int nrawA = cnt[rowgA], nrawB = cnt[rowgA + 1];
  const int nA = nrawA < CAP ? nrawA : CAP;
  const int nB = nrawB < CAP ? nrawB : CAP;
  const int nr   = rr32 ? nB : nA;
  const int nmx  = nA > nB ? nA : nB;
  const bool ovf = (rr32 ? nrawB : nrawA) > CAP;

  const float* Qg = Q + (size_t)rowg * DD;
  const float* Kb = K + (size_t)b * SS * DD;
  const float* Vb = V + (size_t)b * SS * DD;

  // ---- refine EXACTLY: z = 0.5 * dot_f32(Q[row], K[c]), 32 lanes/row ----
  {
    const float4 q4 = *(const float4*)&Qg[l32 * 4];
    for (int i = 0; i < nmx; ++i) {
      const bool act = i < nr;
      const int c = candC[rowg * CAP + (act ? i : 0)];   // nr >= 1 always
      const float4 k4 = *(const float4*)&Kb[(size_t)c * DD + l32 * 4];
      float t = q4.x * k4.x + q4.y * k4.y + q4.z * k4.z + q4.w * k4.w;
#pragma unroll
      for (int s = 1; s <= 16; s <<= 1) t += __shfl_xor(t, s);
      if (act && l32 == 0) zv[w][rr32][i] = 0.5f * t;
    }
  }
  // zv written+read by this same wave only -> no barrier

  // ---- bisection: 32 lanes per row, CAP<=32 -> 1 register ----
  float tau, Zr = 0.f;
  {
    const float a0 = (l32 < nr) ? zv[w][rr32][l32] : -1e38f;
    float Mr = a0;
#pragma unroll
    for (int s = 1; s <= 16; s <<= 1) Mr = fmaxf(Mr, __shfl_xor(Mr, s));
    float tmn = Mr - 1.0f, tmx = Mr - 0.022097086912079608f;  // S^(1-alpha)
    tau = 0.5f * (tmn + tmx);
    for (int it = 0; it < 100; ++it) {
      tau = 0.5f * (tmn + tmx);
      const float t0 = fmaxf(a0 - tau, 0.f);
      float zp = t0 * t0;
#pragma unroll
      for (int s = 1; s <= 16; s <<= 1) zp += __shfl_xor(zp, s);
      Zr = zp;
      const float nmn = (zp >= 1.f) ? tau : tmn;
      const float nmx2 = (zp >= 1.f) ? tmx : tau;
      const bool ch = (nmn != tmn) || (nmx2 != tmx);
      tmn = nmn; tmx = nmx2;
      if (!__any(ch)) break;   // fixed point: faithful to 100 iters
    }
  }

  // ---- fast output: O = sum p_i * V[col_i] ----
  if (!ovf) {
    const float iz = 1.0f / Zr;
    float4 o = {0.f, 0.f, 0.f, 0.f};
    for (int i = 0; i < nr; ++i) {
      const float tt = fmaxf(zv[w][rr32][i] - tau, 0.f);   // LDS broadcast
      const float pi = tt * tt * iz;
      const int   c  = candC[rowg * CAP + i];
      const float4 v4 = *(const float4*)&Vb[(size_t)c * DD + l32 * 4];
      o.x = fmaf(pi, v4.x, o.x);
      o.y = fmaf(pi, v4.y, o.y);
      o.z = fmaf(pi, v4.z, o.z);
      o.w = fmaf(pi, v4.w, o.w);
    }
    *(float4*)&Out[(size_t)rowg * DD + l32 * 4] = o;
  } else if (l32 == 0) {
    ovfs[w * 2 + rr32] = 1;
  }
  __syncthreads();

  // ---- exact dense fallback, block-serialized per overflowed row (~unreachable) ----
  for (int r8 = 0; r8 < 8; ++r8) {
    if (!ovfs[r8]) continue;
    const int fr = blockIdx.x * 8 + r8;
    const int fb = fr >> 11;
    const float* fQ = Q + (size_t)fr * DD;
    const float* fK = K + (size_t)fb * SS * DD;
    const float* fV = V + (size_t)fb * SS * DD;
    for (int c = tid; c < SS; c += 256) {
      float t = 0.f;
      for (int d = 0; d < DD; d += 4) {
        const float4 qv = *(const float4*)&fQ[d];
        const float4 kv = *(const float4*)&fK[(size_t)c * DD + d];
        t = fmaf(qv.x, kv.x, t); t = fmaf(qv.y, kv.y, t);
        t = fmaf(qv.z, kv.z, t); t = fmaf(qv.w, kv.w, t);
      }
      zscr[c] = 0.5f * t;
    }
    __syncthreads();
    if (w == 0) {                              // wave 0 bisects from LDS
      float Mr = -1e38f;
      for (int c0 = 0; c0 < 32; ++c0) Mr = fmaxf(Mr, zscr[c0 * 64 + lane]);
#pragma unroll
      for (int s = 1; s <= 32; s <<= 1) Mr = fmaxf(Mr, __shfl_xor(Mr, s));
      float tmn = Mr - 1.0f, tmx = Mr - 0.022097086912079608f;
      float ta = 0.5f * (tmn + tmx), Zf = 0.f;
      for (int it = 0; it < 100; ++it) {
        ta = 0.5f * (tmn + tmx);
        float zp = 0.f;
        for (int c0 = 0; c0 < 32; ++c0) {
          const float tt = fmaxf(zscr[c0 * 64 + lane] - ta, 0.f);
          zp = fmaf(tt, tt, zp);
        }
#pragma unroll
        for (int s = 1; s <= 32; s <<= 1) zp += __shfl_xor(zp, s);
        Zf = zp;
        const float nmn = (zp >= 1.f) ? ta : tmn;
        const float nmx2 = (zp >= 1.f) ? tmx : ta;
        const bool ch = (nmn != tmn) || (nmx2 != tmx);
        tmn = nmn; tmx = nmx2;
        if (!__any(ch)) break;
      }
      if (lane == 0) { ftau = ta; fZ = Zf; }
    }
    __syncthreads();
    if (tid < DD) {
      const float ta = ftau, iz = 1.0f / fZ;
      float o = 0.f;
      for (int c = 0; c < SS; ++c) {
        const float tt = fmaxf(zscr[c] - ta, 0.f);
        if (tt > 0.f) o = fmaf(tt * tt * iz, fV[(size_t)c * DD + tid], o);
      }
      Out[(size_t)fr * DD + tid] = o;
    }
    __syncthreads();                           // zscr reused by next row
  }
}

extern "C" void kernel_launch(void* const* d_in, const int* in_sizes, int n_in,
                              void* d_out, int out_size, void* d_ws, size_t ws_size,
                              hipStream_t stream) {
  const float* Q = (const float*)d_in[0];
  const float* K = (const float*)d_in[1];
  const float* V = (const float*)d_in[2];
  float* out = (float*)d_out;
  short* Khi  = (short*)d_ws;                                  // 4 MiB
  int*   candC = (int*)((char*)d_ws + (size_t)BB * SS * DD * 2); // 1.5 MiB
  int*   cnt   = candC + (size_t)BB * SS * CAP;                  // 64 KiB

  hipLaunchKernelGGL(ksplit, dim3(BB * SS * DD / (256 * 8)), dim3(256), 0, stream,
                     K, Khi, cnt);
  hipLaunchKernelGGL(screen, dim3(BB * (SS / ROWS)), dim3(512), 0, stream,
                     Q, Khi, candC, cnt);
  hipLaunchKernelGGL(tail, dim3(BB * SS / 8), dim3(256), 0, stream,
                     Q, K, V, candC, cnt, out);
}

// Round 7
// 127.176 us; speedup vs baseline: 1.2026x; 1.1089x over previous
//
#include <hip/hip_runtime.h>

#define BB 8
#define SS 2048
#define DD 128
#define ROWS 16            // q rows per block
#define NW 8               // waves per block (512 threads)
#define CTW 16             // col-tiles (of 16) per wave -> 256 cols/wave

typedef short bf16x8 __attribute__((ext_vector_type(8)));
typedef float f32x4 __attribute__((ext_vector_type(4)));

template <int I> struct IC { static constexpr int value = I; };
template <int I, int N, typename F>
__device__ __forceinline__ void sfor(F&& f) {
  if constexpr (I < N) { f(IC<I>{}); sfor<I + 1, N>((F&&)f); }
}

__device__ __forceinline__ short f2bf(float x) {
  return __builtin_bit_cast(short, (__bf16)x);
}

// async DMA one 1KB segment: 64 lanes x 16B, LDS dest = uniform base + lane*16
__device__ __forceinline__ void stage_tile(const short* g, short* l) {
#pragma unroll
  for (int s = 0; s < 4; ++s) {
    __builtin_amdgcn_global_load_lds(
        (const __attribute__((address_space(1))) void*)(g + (s << 9)),
        (__attribute__((address_space(3))) void*)(l + (s << 9)), 16, 0, 0);
  }
}

// ---- prep: Khi = bf16(K) in MFMA B-fragment order; READ-COALESCED ----
// thread -> 8 consecutive floats of K; wave reads 8KB contiguous.
// Output line (64B) = 4 threads with consecutive rows (m16) of same wave.
__global__ __launch_bounds__(256)
void ksplit(const float* __restrict__ K, short* __restrict__ Khi) {
  const int lin = blockIdx.x * 256 + threadIdx.x;    // 262144 chunks of 8
  const int r   = lin >> 4;                          // global K row (b*2048+row)
  const int c8  = lin & 15;                          // which 8-float chunk
  const float4 v0 = *(const float4*)(K + (size_t)lin * 8);
  const float4 v1 = *(const float4*)(K + (size_t)lin * 8 + 4);
  bf16x8 h;
  h[0] = f2bf(v0.x); h[1] = f2bf(v0.y); h[2] = f2bf(v0.z); h[3] = f2bf(v0.w);
  h[4] = f2bf(v1.x); h[5] = f2bf(v1.y); h[6] = f2bf(v1.z); h[7] = f2bf(v1.w);
  // frag addr: (b, ct, s, lane=quad*16+m16) ; d = c8*8 -> s=c8>>2, quad=c8&3
  const int bct  = r >> 4;                           // b*128 + ct
  const int m16  = r & 15;
  const int s    = c8 >> 2;
  const int quad = c8 & 3;
  const size_t out = ((((size_t)bct * 4 + s) * 64) + quad * 16 + m16) * 8;
  *(bf16x8*)(Khi + out) = h;
}

// ---- fused entmax attention: R2 structure (2-slot full-tile ring), spill-free ----
__global__ __launch_bounds__(512) __attribute__((amdgpu_waves_per_eu(3, 4)))
void attn(const float* __restrict__ Q, const short* __restrict__ Khi,
          const float* __restrict__ K, const float* __restrict__ V,
          float* __restrict__ Out) {
  __shared__ short kring[NW][2][2048];         // per-wave 2-slot 4KB-tile ring (64 KiB)
  __shared__ unsigned short Qs[ROWS][136];     // bf16(0.5*Q), A-operand layout
  __shared__ float rbuf[ROWS][64];             // candidate VALUES (then exact)
  __shared__ int   scol[ROWS][64];             // candidate COLUMNS
  __shared__ float exM[NW][ROWS];
  __shared__ int   rcnt[ROWS];
  __shared__ int   rovf[ROWS];                 // per-row overflow flag
  __shared__ float tauB[ROWS], ZB[ROWS];

  const int tid  = threadIdx.x;
  const int lane = tid & 63;
  const int wid  = __builtin_amdgcn_readfirstlane(tid >> 6);  // 0..7
  const int quad = lane >> 4, m16 = lane & 15;
  const int b    = blockIdx.x & 7;             // batch -> XCD pinning
  const int qt   = blockIdx.x >> 3;            // 0..127

  const float* Qb = Q + (size_t)(b * SS + qt * ROWS) * DD;
  const float* Kb = K + (size_t)b * SS * DD;
  const float* Vb = V + (size_t)b * SS * DD;
  float*       Ob = Out + (size_t)(b * SS + qt * ROWS) * DD;
  const short* KHb = Khi + (size_t)b * SS * DD;

  if (tid < ROWS) { rcnt[tid] = 0; rovf[tid] = 0; }

  // ---- stage Q once: bf16(0.5*q), A-operand layout ----
  {
    const int row = tid >> 5, d = (tid & 31) * 4;
    const float4 v = *(const float4*)&Qb[row * DD + d];
    ushort4 h;
    h.x = (unsigned short)f2bf(0.5f * v.x);
    h.y = (unsigned short)f2bf(0.5f * v.y);
    h.z = (unsigned short)f2bf(0.5f * v.z);
    h.w = (unsigned short)f2bf(0.5f * v.w);
    *(ushort4*)&Qs[row][d] = h;
  }
  __syncthreads();   // also drains vmcnt -> ring counting below starts clean

  bf16x8 qh[4];
#pragma unroll
  for (int s = 0; s < 4; ++s)
    qh[s] = *(const bf16x8*)&Qs[m16][s * 32 + quad * 8];

  // ---- phase 1: z_a = bf16(0.5Q) * Khi^T via per-wave async LDS ring ----
  // wave 'wid' owns tiles ct = wid*16 + i; tiles consumed only by loader wave.
  short* ring0 = &kring[wid][0][0];
  short* ring1 = &kring[wid][1][0];
  const short* gw = KHb + ((size_t)(wid * CTW) << 11) + lane * 8;

  stage_tile(gw + 0 * 2048, ring0);
  stage_tile(gw + 1 * 2048, ring1);

  f32x4 acc[CTW];
  sfor<0, CTW>([&](auto ic) {
    constexpr int i = ic.value;
    if constexpr (i < CTW - 1) asm volatile("s_waitcnt vmcnt(4)" ::: "memory");
    else                       asm volatile("s_waitcnt vmcnt(0)" ::: "memory");
    const short* sbl = ((i & 1) ? ring1 : ring0) + lane * 8;
    f32x4 c = {0.f, 0.f, 0.f, 0.f};
    sfor<0, 4>([&](auto sc) {
      constexpr int s = sc.value;
      const bf16x8 bh = *(const bf16x8*)(sbl + (s << 9));
      c = __builtin_amdgcn_mfma_f32_16x16x32_bf16(qh[s], bh, c, 0, 0, 0);
    });
    acc[i] = c;
    if constexpr (i + 2 < CTW) {
      asm volatile("s_waitcnt lgkmcnt(0)" ::: "memory");  // reads retired
      stage_tile(gw + (i + 2) * 2048, (i & 1) ? ring1 : ring0);
    }
  });
  // lane holds z_a[row=4*quad+j][col = wid*256 + i*16 + m16]; |z_a - z| std ~0.009

  // ---- row max of z_a ----
  float mx[4] = {-1e38f, -1e38f, -1e38f, -1e38f};
  sfor<0, CTW>([&](auto ic) {
#pragma unroll
    for (int j = 0; j < 4; ++j) mx[j] = fmaxf(mx[j], acc[ic.value][j]);
  });
#pragma unroll
  for (int j = 0; j < 4; ++j)
#pragma unroll
    for (int s = 1; s <= 8; s <<= 1) mx[j] = fmaxf(mx[j], __shfl_xor(mx[j], s));
  if (m16 == 0) {
#pragma unroll
    for (int j = 0; j < 4; ++j) exM[wid][4 * quad + j] = mx[j];
  }
  __syncthreads();
  float M4[4];
#pragma unroll
  for (int j = 0; j < 4; ++j) {
    float m = -1e38f;
#pragma unroll
    for (int w = 0; w < NW; ++w) m = fmaxf(m, exM[w][4 * quad + j]);
    M4[j] = m;
  }

  // ---- compact candidates: z_a > M - 1.25 (margin = 1 + ~13 sigma of z_a err) ----
  sfor<0, CTW>([&](auto ic) {
    constexpr int i = ic.value;
    const int col = wid * 256 + i * 16 + m16;
#pragma unroll
    for (int j = 0; j < 4; ++j) {
      const int row = 4 * quad + j;
      if (acc[i][j] > M4[j] - 1.25f) {
        const int pos = atomicAdd(&rcnt[row], 1);
        if (pos < 64) { scol[row][pos] = col; rbuf[row][pos] = acc[i][j]; }
        else rovf[row] = 1;
      }
    }
  });
  __syncthreads();   // candidate tables complete; acc dead from here

  // ======== wave-local tail: wave wid owns rows 2*wid, 2*wid+1 ========
  const int rr32 = lane >> 5;                  // which of this wave's rows
  const int row  = 2 * wid + rr32;
  const int l32  = lane & 31;
  const int nA = rcnt[2 * wid]     < 64 ? rcnt[2 * wid]     : 64;
  const int nB = rcnt[2 * wid + 1] < 64 ? rcnt[2 * wid + 1] : 64;
  const int nr  = rr32 ? nB : nA;
  const int nmx = nA > nB ? nA : nB;

  // ---- refine EXACTLY (2 rows in parallel, 32 lanes each): z = 0.5*dot ----
  {
    const float4 q4 = *(const float4*)&Qb[row * DD + l32 * 4];
    for (int i = 0; i < nmx; ++i) {
      const bool act = i < nr;
      const int c = act ? scol[row][i] : scol[row][0];
      const float4 k4 = *(const float4*)&Kb[(size_t)c * DD + l32 * 4];
      float t = q4.x * k4.x + q4.y * k4.y + q4.z * k4.z + q4.w * k4.w;
#pragma unroll
      for (int s = 1; s <= 16; s <<= 1) t += __shfl_xor(t, s);
      if (act && l32 == 0) rbuf[row][i] = 0.5f * t;
    }
  }
  // rbuf written+read by this same wave only -> no barrier

  // ---- bisection: 32 lanes per row, candidates in 2 registers ----
  {
    const float a0 = (l32 < nr)      ? rbuf[row][l32]      : -1e38f;
    const float a1 = (l32 + 32 < nr) ? rbuf[row][l32 + 32] : -1e38f;
    float Mr = fmaxf(a0, a1);
#pragma unroll
    for (int s = 1; s <= 16; s <<= 1) Mr = fmaxf(Mr, __shfl_xor(Mr, s));
    float tmn = Mr - 1.0f, tmx = Mr - 0.022097086912079608f;  // S^(1-alpha)
    float tau = 0.5f * (tmn + tmx), Zr = 0.f;
    for (int it = 0; it < 100; ++it) {
      tau = 0.5f * (tmn + tmx);
      const float t0 = fmaxf(a0 - tau, 0.f);
      const float t1 = fmaxf(a1 - tau, 0.f);
      float zp = fmaf(t0, t0, t1 * t1);
#pragma unroll
      for (int s = 1; s <= 16; s <<= 1) zp += __shfl_xor(zp, s);
      Zr = zp;
      const float nmn = (zp >= 1.f) ? tau : tmn;
      const float nmx2 = (zp >= 1.f) ? tmx : tau;
      const bool ch = (nmn != tmn) || (nmx2 != tmx);
      tmn = nmn; tmx = nmx2;
      if (!__any(ch)) break;   // fixed point: faithful to 100 iters
    }
    if (l32 == 0) { tauB[row] = tau; ZB[row] = Zr; }
  }

  // ---- fast output (2 rows in parallel): O = sum p_i * V[col_i] ----
  if (!rovf[row]) {
    const float tau = tauB[row];
    const float iz  = 1.0f / ZB[row];
    float4 o = {0.f, 0.f, 0.f, 0.f};
    for (int i = 0; i < nr; ++i) {
      const float rv = rbuf[row][i];           // same addr per half -> broadcast
      const float tt = fmaxf(rv - tau, 0.f);
      const float pi = tt * tt * iz;
      const int   c  = scol[row][i];
      const float4 v4 = *(const float4*)&Vb[(size_t)c * DD + l32 * 4];
      o.x = fmaf(pi, v4.x, o.x);
      o.y = fmaf(pi, v4.y, o.y);
      o.z = fmaf(pi, v4.z, o.z);
      o.w = fmaf(pi, v4.w, o.w);
    }
    *(float4*)&Ob[row * DD + l32 * 4] = o;
  }

  // ---- exact wave-local dense fallback (candidate overflow; ~unreachable) ----
#pragma unroll
  for (int rr = 0; rr < 2; ++rr) {
    const int frow = 2 * wid + rr;
    if (!rovf[frow]) continue;
    float* zr = (float*)&kring[wid][0][0];     // 8 KB = 2048 f32, wave-private
    for (int c0 = 0; c0 < 32; ++c0) {
      const int c = c0 * 64 + lane;
      const float* kp = &Kb[(size_t)c * DD];
      float t = 0.f;
      for (int d = 0; d < DD; d += 4) {
        const float4 qv = *(const float4*)&Qb[frow * DD + d];
        const float4 kv = *(const float4*)&kp[d];
        t = fmaf(qv.x, kv.x, t); t = fmaf(qv.y, kv.y, t);
        t = fmaf(qv.z, kv.z, t); t = fmaf(qv.w, kv.w, t);
      }
      zr[c] = 0.5f * t;
    }
    float Mr = -1e38f;
    for (int c0 = 0; c0 < 32; ++c0) Mr = fmaxf(Mr, zr[c0 * 64 + lane]);
#pragma unroll
    for (int s = 1; s <= 32; s <<= 1) Mr = fmaxf(Mr, __shfl_xor(Mr, s));
    float tmn = Mr - 1.0f, tmx = Mr - 0.022097086912079608f;
    float tau = 0.5f * (tmn + tmx), Zr = 0.f;
    for (int it = 0; it < 100; ++it) {
      tau = 0.5f * (tmn + tmx);
      float zp = 0.f;
      for (int c0 = 0; c0 < 32; ++c0) {
        const float tt = fmaxf(zr[c0 * 64 + lane] - tau, 0.f);
        zp = fmaf(tt, tt, zp);
      }
#pragma unroll
      for (int s = 1; s <= 32; s <<= 1) zp += __shfl_xor(zp, s);
      Zr = zp;
      const float nmn = (zp >= 1.f) ? tau : tmn;
      const float nmx2 = (zp >= 1.f) ? tmx : tau;
      const bool ch = (nmn != tmn) || (nmx2 != tmx);
      tmn = nmn; tmx = nmx2;
      if (!__any(ch)) break;
    }
    const float iz = 1.0f / Zr;
    float2 o = {0.f, 0.f};
    for (int c = 0; c < SS; ++c) {
      const float tt = fmaxf(zr[c] - tau, 0.f);   // broadcast -> uniform branch
      if (tt > 0.f) {
        const float pi = tt * tt * iz;
        const float2 v2 = *(const float2*)&Vb[(size_t)c * DD + lane * 2];
        o.x = fmaf(pi, v2.x, o.x);
        o.y = fmaf(pi, v2.y, o.y);
      }
    }
    *(float2*)&Ob[frow * DD + lane * 2] = o;
  }
}

extern "C" void kernel_launch(void* const* d_in, const int* in_sizes, int n_in,
                              void* d_out, int out_size, void* d_ws, size_t ws_size,
                              hipStream_t stream) {
  const float* Q = (const float*)d_in[0];
  const float* K = (const float*)d_in[1];
  const float* V = (const float*)d_in[2];
  float* out = (float*)d_out;
  short* Khi = (short*)d_ws;                      // 4 MiB, fragment order

  hipLaunchKernelGGL(ksplit, dim3(BB * SS * DD / (256 * 8)), dim3(256), 0, stream,
                     K, Khi);
  hipLaunchKernelGGL(attn, dim3(BB * (SS / ROWS)), dim3(512), 0, stream,
                     Q, Khi, K, V, out);
}

// Round 8
// 117.155 us; speedup vs baseline: 1.3055x; 1.0855x over previous
//
#include <hip/hip_runtime.h>

#define BB 8
#define SS 2048
#define DD 128
#define ROWS 16            // q rows per block
#define NW 8               // waves per block (512 threads)
#define CTW 16             // col-tiles (of 16) per wave -> 256 cols/wave

typedef short bf16x8 __attribute__((ext_vector_type(8)));
typedef float f32x4 __attribute__((ext_vector_type(4)));

template <int I> struct IC { static constexpr int value = I; };
template <int I, int N, typename F>
__device__ __forceinline__ void sfor(F&& f) {
  if constexpr (I < N) { f(IC<I>{}); sfor<I + 1, N>((F&&)f); }
}

__device__ __forceinline__ short f2bf(float x) {
  return __builtin_bit_cast(short, (__bf16)x);
}

// async DMA one 1KB segment: 64 lanes x 16B, LDS dest = uniform base + lane*16
__device__ __forceinline__ void stage_tile(const short* g, short* l) {
#pragma unroll
  for (int s = 0; s < 4; ++s) {
    __builtin_amdgcn_global_load_lds(
        (const __attribute__((address_space(1))) void*)(g + (s << 9)),
        (__attribute__((address_space(3))) void*)(l + (s << 9)), 16, 0, 0);
  }
}

// ---- prep: Khi = bf16(K) in MFMA B-fragment order; READ-COALESCED ----
__global__ __launch_bounds__(256)
void ksplit(const float* __restrict__ K, short* __restrict__ Khi) {
  const int lin = blockIdx.x * 256 + threadIdx.x;    // 262144 chunks of 8
  const int r   = lin >> 4;                          // global K row (b*2048+row)
  const int c8  = lin & 15;                          // which 8-float chunk
  const float4 v0 = *(const float4*)(K + (size_t)lin * 8);
  const float4 v1 = *(const float4*)(K + (size_t)lin * 8 + 4);
  bf16x8 h;
  h[0] = f2bf(v0.x); h[1] = f2bf(v0.y); h[2] = f2bf(v0.z); h[3] = f2bf(v0.w);
  h[4] = f2bf(v1.x); h[5] = f2bf(v1.y); h[6] = f2bf(v1.z); h[7] = f2bf(v1.w);
  const int bct  = r >> 4;                           // b*128 + ct
  const int m16  = r & 15;
  const int s    = c8 >> 2;
  const int quad = c8 & 3;
  const size_t out = ((((size_t)bct * 4 + s) * 64) + quad * 16 + m16) * 8;
  *(bf16x8*)(Khi + out) = h;
}

// ---- fused entmax attention: R7 structure + closed-form threshold ----
__global__ __launch_bounds__(512) __attribute__((amdgpu_waves_per_eu(3, 4)))
void attn(const float* __restrict__ Q, const short* __restrict__ Khi,
          const float* __restrict__ K, const float* __restrict__ V,
          float* __restrict__ Out) {
  __shared__ short kring[NW][2][2048];         // per-wave 2-slot 4KB-tile ring (64 KiB)
  __shared__ unsigned short Qs[ROWS][136];     // bf16(0.5*Q), A-operand layout
  __shared__ float rbuf[ROWS][64];             // candidate VALUES (then exact)
  __shared__ int   scol[ROWS][64];             // candidate COLUMNS
  __shared__ float exM[NW][ROWS];
  __shared__ int   rcnt[ROWS];
  __shared__ int   rovf[ROWS];                 // per-row overflow flag
  __shared__ float tauB[ROWS], ZB[ROWS];

  const int tid  = threadIdx.x;
  const int lane = tid & 63;
  const int wid  = __builtin_amdgcn_readfirstlane(tid >> 6);  // 0..7
  const int quad = lane >> 4, m16 = lane & 15;
  const int b    = blockIdx.x & 7;             // batch -> XCD pinning
  const int qt   = blockIdx.x >> 3;            // 0..127

  const float* Qb = Q + (size_t)(b * SS + qt * ROWS) * DD;
  const float* Kb = K + (size_t)b * SS * DD;
  const float* Vb = V + (size_t)b * SS * DD;
  float*       Ob = Out + (size_t)(b * SS + qt * ROWS) * DD;
  const short* KHb = Khi + (size_t)b * SS * DD;

  if (tid < ROWS) { rcnt[tid] = 0; rovf[tid] = 0; }

  // ---- stage Q once: bf16(0.5*q), A-operand layout ----
  {
    const int row = tid >> 5, d = (tid & 31) * 4;
    const float4 v = *(const float4*)&Qb[row * DD + d];
    ushort4 h;
    h.x = (unsigned short)f2bf(0.5f * v.x);
    h.y = (unsigned short)f2bf(0.5f * v.y);
    h.z = (unsigned short)f2bf(0.5f * v.z);
    h.w = (unsigned short)f2bf(0.5f * v.w);
    *(ushort4*)&Qs[row][d] = h;
  }
  __syncthreads();   // also drains vmcnt -> ring counting below starts clean

  bf16x8 qh[4];
#pragma unroll
  for (int s = 0; s < 4; ++s)
    qh[s] = *(const bf16x8*)&Qs[m16][s * 32 + quad * 8];

  // ---- phase 1: z_a = bf16(0.5Q) * Khi^T via per-wave async LDS ring ----
  short* ring0 = &kring[wid][0][0];
  short* ring1 = &kring[wid][1][0];
  const short* gw = KHb + ((size_t)(wid * CTW) << 11) + lane * 8;

  stage_tile(gw + 0 * 2048, ring0);
  stage_tile(gw + 1 * 2048, ring1);

  f32x4 acc[CTW];
  sfor<0, CTW>([&](auto ic) {
    constexpr int i = ic.value;
    if constexpr (i < CTW - 1) asm volatile("s_waitcnt vmcnt(4)" ::: "memory");
    else                       asm volatile("s_waitcnt vmcnt(0)" ::: "memory");
    const short* sbl = ((i & 1) ? ring1 : ring0) + lane * 8;
    f32x4 c = {0.f, 0.f, 0.f, 0.f};
    sfor<0, 4>([&](auto sc) {
      constexpr int s = sc.value;
      const bf16x8 bh = *(const bf16x8*)(sbl + (s << 9));
      c = __builtin_amdgcn_mfma_f32_16x16x32_bf16(qh[s], bh, c, 0, 0, 0);
    });
    acc[i] = c;
    if constexpr (i + 2 < CTW) {
      asm volatile("s_waitcnt lgkmcnt(0)" ::: "memory");  // reads retired
      stage_tile(gw + (i + 2) * 2048, (i & 1) ? ring1 : ring0);
    }
  });

  // ---- row max of z_a ----
  float mx[4] = {-1e38f, -1e38f, -1e38f, -1e38f};
  sfor<0, CTW>([&](auto ic) {
#pragma unroll
    for (int j = 0; j < 4; ++j) mx[j] = fmaxf(mx[j], acc[ic.value][j]);
  });
#pragma unroll
  for (int j = 0; j < 4; ++j)
#pragma unroll
    for (int s = 1; s <= 8; s <<= 1) mx[j] = fmaxf(mx[j], __shfl_xor(mx[j], s));
  if (m16 == 0) {
#pragma unroll
    for (int j = 0; j < 4; ++j) exM[wid][4 * quad + j] = mx[j];
  }
  __syncthreads();
  float M4[4];
#pragma unroll
  for (int j = 0; j < 4; ++j) {
    float m = -1e38f;
#pragma unroll
    for (int w = 0; w < NW; ++w) m = fmaxf(m, exM[w][4 * quad + j]);
    M4[j] = m;
  }

  // ---- compact candidates: z_a > M - 1.25 (margin = 1 + ~13 sigma of z_a err) ----
  sfor<0, CTW>([&](auto ic) {
    constexpr int i = ic.value;
    const int col = wid * 256 + i * 16 + m16;
#pragma unroll
    for (int j = 0; j < 4; ++j) {
      const int row = 4 * quad + j;
      if (acc[i][j] > M4[j] - 1.25f) {
        const int pos = atomicAdd(&rcnt[row], 1);
        if (pos < 64) { scol[row][pos] = col; rbuf[row][pos] = acc[i][j]; }
        else rovf[row] = 1;
      }
    }
  });
  __syncthreads();   // candidate tables complete; acc dead from here

  // ======== wave-local tail: wave wid owns rows 2*wid, 2*wid+1 ========
  const int rr32 = lane >> 5;                  // which of this wave's rows
  const int row  = 2 * wid + rr32;
  const int l32  = lane & 31;
  const int nA = rcnt[2 * wid]     < 64 ? rcnt[2 * wid]     : 64;
  const int nB = rcnt[2 * wid + 1] < 64 ? rcnt[2 * wid + 1] : 64;
  const int nr  = rr32 ? nB : nA;
  const int nmx = nA > nB ? nA : nB;

  // ---- refine EXACTLY (2 rows in parallel, 32 lanes each): z = 0.5*dot ----
  {
    const float4 q4 = *(const float4*)&Qb[row * DD + l32 * 4];
    for (int i = 0; i < nmx; ++i) {
      const bool act = i < nr;
      const int c = act ? scol[row][i] : scol[row][0];
      const float4 k4 = *(const float4*)&Kb[(size_t)c * DD + l32 * 4];
      float t = q4.x * k4.x + q4.y * k4.y + q4.z * k4.z + q4.w * k4.w;
#pragma unroll
      for (int s = 1; s <= 16; s <<= 1) t += __shfl_xor(t, s);
      if (act && l32 == 0) rbuf[row][i] = 0.5f * t;
    }
  }
  // rbuf written+read by this same wave only -> no barrier

  // ---- closed-form entmax-1.5 threshold (replaces 100-iter bisection) ----
  // For support size k: tau_k = (S1k - sqrt(S1k^2 - k(S2k-1)))/k; valid iff
  // z_(k) > tau_k >= z_(k+1). Each lane tests its own candidate(s) as the
  // minimum support element via one LDS-broadcast pass (no sort).
  {
    const float z0 = (l32 < nr)      ? rbuf[row][l32]      : -1e38f;
    const float z1 = (l32 + 32 < nr) ? rbuf[row][l32 + 32] : -1e38f;
    float k0 = 0.f, S10 = 0.f, S20 = 0.f, nb0 = -1e38f;
    float k1 = 0.f, S11 = 0.f, S21 = 0.f, nb1 = -1e38f;
    for (int j = 0; j < nr; ++j) {
      const float w = rbuf[row][j];            // same addr per half -> broadcast
      // total order: value desc, slot index asc (slot of z0 is l32, z1 is l32+32)
      const bool ge0 = (w > z0) || (w == z0 && j <= l32);
      k0  += ge0 ? 1.f : 0.f;
      S10 += ge0 ? w : 0.f;
      S20  = ge0 ? fmaf(w, w, S20) : S20;
      nb0  = (!ge0 && w > nb0) ? w : nb0;
      const bool ge1 = (w > z1) || (w == z1 && j <= l32 + 32);
      k1  += ge1 ? 1.f : 0.f;
      S11 += ge1 ? w : 0.f;
      S21  = ge1 ? fmaf(w, w, S21) : S21;
      nb1  = (!ge1 && w > nb1) ? w : nb1;
    }
    const float d0 = fmaxf(fmaf(S10, S10, -k0 * (S20 - 1.f)), 0.f);
    const float d1 = fmaxf(fmaf(S11, S11, -k1 * (S21 - 1.f)), 0.f);
    const float tau0 = (S10 - __builtin_sqrtf(d0)) / fmaxf(k0, 1.f);
    const float tau1 = (S11 - __builtin_sqrtf(d1)) / fmaxf(k1, 1.f);
    const bool v0b = z0 > tau0, v1b = z1 > tau1;           // necessary cond
    const bool v0  = v0b && (nb0 <= tau0);                 // full support cond
    const bool v1  = v1b && (nb1 <= tau1);
    float tv = fmaxf(v0 ? tau0 : -1e38f, v1 ? tau1 : -1e38f);
    float tb = fmaxf(v0b ? tau0 : -1e38f, v1b ? tau1 : -1e38f);
#pragma unroll
    for (int s = 1; s <= 16; s <<= 1) {
      tv = fmaxf(tv, __shfl_xor(tv, s));
      tb = fmaxf(tb, __shfl_xor(tb, s));
    }
    const float tau = (tv > -1e37f) ? tv : tb;             // fp-edge insurance
    const float p0 = fmaxf(z0 - tau, 0.f);
    const float p1 = fmaxf(z1 - tau, 0.f);
    float zp = fmaf(p0, p0, p1 * p1);
#pragma unroll
    for (int s = 1; s <= 16; s <<= 1) zp += __shfl_xor(zp, s);
    if (l32 == 0) { tauB[row] = tau; ZB[row] = zp; }
  }

  // ---- fast output (2 rows in parallel): O = sum p_i * V[col_i] ----
  if (!rovf[row]) {
    const float tau = tauB[row];
    const float iz  = 1.0f / ZB[row];
    float4 o = {0.f, 0.f, 0.f, 0.f};
    for (int i = 0; i < nr; ++i) {
      const float rv = rbuf[row][i];           // same addr per half -> broadcast
      const float tt = fmaxf(rv - tau, 0.f);
      const float pi = tt * tt * iz;
      const int   c  = scol[row][i];
      const float4 v4 = *(const float4*)&Vb[(size_t)c * DD + l32 * 4];
      o.x = fmaf(pi, v4.x, o.x);
      o.y = fmaf(pi, v4.y, o.y);
      o.z = fmaf(pi, v4.z, o.z);
      o.w = fmaf(pi, v4.w, o.w);
    }
    *(float4*)&Ob[row * DD + l32 * 4] = o;
  }

  // ---- exact wave-local dense fallback (candidate overflow; ~unreachable) ----
#pragma unroll
  for (int rr = 0; rr < 2; ++rr) {
    const int frow = 2 * wid + rr;
    if (!rovf[frow]) continue;
    float* zr = (float*)&kring[wid][0][0];     // 8 KB = 2048 f32, wave-private
    for (int c0 = 0; c0 < 32; ++c0) {
      const int c = c0 * 64 + lane;
      const float* kp = &Kb[(size_t)c * DD];
      float t = 0.f;
      for (int d = 0; d < DD; d += 4) {
        const float4 qv = *(const float4*)&Qb[frow * DD + d];
        const float4 kv = *(const float4*)&kp[d];
        t = fmaf(qv.x, kv.x, t); t = fmaf(qv.y, kv.y, t);
        t = fmaf(qv.z, kv.z, t); t = fmaf(qv.w, kv.w, t);
      }
      zr[c] = 0.5f * t;
    }
    float Mr = -1e38f;
    for (int c0 = 0; c0 < 32; ++c0) Mr = fmaxf(Mr, zr[c0 * 64 + lane]);
#pragma unroll
    for (int s = 1; s <= 32; s <<= 1) Mr = fmaxf(Mr, __shfl_xor(Mr, s));
    float tmn = Mr - 1.0f, tmx = Mr - 0.022097086912079608f;
    float tau = 0.5f * (tmn + tmx), Zr = 0.f;
    for (int it = 0; it < 100; ++it) {
      tau = 0.5f * (tmn + tmx);
      float zp = 0.f;
      for (int c0 = 0; c0 < 32; ++c0) {
        const float tt = fmaxf(zr[c0 * 64 + lane] - tau, 0.f);
        zp = fmaf(tt, tt, zp);
      }
#pragma unroll
      for (int s = 1; s <= 32; s <<= 1) zp += __shfl_xor(zp, s);
      Zr = zp;
      const float nmn = (zp >= 1.f) ? tau : tmn;
      const float nmx2 = (zp >= 1.f) ? tmx : tau;
      const bool ch = (nmn != tmn) || (nmx2 != tmx);
      tmn = nmn; tmx = nmx2;
      if (!__any(ch)) break;
    }
    const float iz = 1.0f / Zr;
    float2 o = {0.f, 0.f};
    for (int c = 0; c < SS; ++c) {
      const float tt = fmaxf(zr[c] - tau, 0.f);   // broadcast -> uniform branch
      if (tt > 0.f) {
        const float pi = tt * tt * iz;
        const float2 v2 = *(const float2*)&Vb[(size_t)c * DD + lane * 2];
        o.x = fmaf(pi, v2.x, o.x);
        o.y = fmaf(pi, v2.y, o.y);
      }
    }
    *(float2*)&Ob[frow * DD + lane * 2] = o;
  }
}

extern "C" void kernel_launch(void* const* d_in, const int* in_sizes, int n_in,
                              void* d_out, int out_size, void* d_ws, size_t ws_size,
                              hipStream_t stream) {
  const float* Q = (const float*)d_in[0];
  const float* K = (const float*)d_in[1];
  const float* V = (const float*)d_in[2];
  float* out = (float*)d_out;
  short* Khi = (short*)d_ws;                      // 4 MiB, fragment order

  hipLaunchKernelGGL(ksplit, dim3(BB * SS * DD / (256 * 8)), dim3(256), 0, stream,
                     K, Khi);
  hipLaunchKernelGGL(attn, dim3(BB * (SS / ROWS)), dim3(512), 0, stream,
                     Q, Khi, K, V, out);
}